// Round 2
// 607.364 us; speedup vs baseline: 1.0749x; 1.0749x over previous
//
#include <hip/hip_runtime.h>

// Problem constants (fixed by reference setup_inputs)
#define B_ 4
#define N_ 32768       // points per batch
#define C_ 128         // channels
#define D_ 32          // cubic dim
#define V_ (D_ * D_ * D_)   // 32768 voxels

// Native vector type: required by __builtin_nontemporal_{load,store}
// (HIP's float4 is a struct and is rejected).
typedef float f4 __attribute__((ext_vector_type(4)));

// ---------------------------------------------------------------------------
// Kernel 1: transpose (B, C, V) -> (B, V, C), fully vectorized.
// Tile: 128 channels x 32 voxels. float4 global loads (along V, the
// contiguous input dim) and float4 global stores (along C, the contiguous
// output dim). LDS layout [c][v] with stride 33 words:
//   - fill side: ds_write_b128, bank = (c + 4*vq) % 32 -> worst 2-way (free)
//   - drain side: 4x ds_read_b32 stride 33 -> 4-way (1.58x, ~4 us total; LDS
//     traffic is negligible vs 128 MiB of HBM)
// ---------------------------------------------------------------------------
__global__ __launch_bounds__(256) void transpose_kernel(
    const float* __restrict__ in,   // (B, C, V)
    float* __restrict__ out)        // (B, V, C)
{
    __shared__ float lds[C_ * 33];
    const int b  = blockIdx.y;
    const int v0 = blockIdx.x * 32;
    const float* inb  = in  + (size_t)b * C_ * V_;
    float*       outb = out + (size_t)b * C_ * V_;
    const int t = threadIdx.x;

    // ---- read phase: 128 rows x 8 float4 = 1024 float4, 4 per thread ----
    const int vq = t & 7;     // float4 index along v (0..7 -> v = 4*vq)
    const int ci = t >> 3;    // 0..31
#pragma unroll
    for (int r = 0; r < 4; ++r) {
        const int c = ci + r * 32;
        const f4 f = __builtin_nontemporal_load(
            reinterpret_cast<const f4*>(inb + (size_t)c * V_ + v0 + vq * 4));
        float* d = &lds[c * 33 + vq * 4];
        d[0] = f.x; d[1] = f.y; d[2] = f.z; d[3] = f.w;
    }

    __syncthreads();

    // ---- write phase: 32 rows x 32 float4 = 1024 float4, 4 per thread ----
    const int c4 = (t & 31) << 2;  // channel quad
    const int vr = t >> 5;         // 0..7
#pragma unroll
    for (int r = 0; r < 4; ++r) {
        const int v = vr + r * 8;
        f4 g;
        g.x = lds[(c4 + 0) * 33 + v];
        g.y = lds[(c4 + 1) * 33 + v];
        g.z = lds[(c4 + 2) * 33 + v];
        g.w = lds[(c4 + 3) * 33 + v];
        // featsT is re-read by the gather: keep it cacheable (default store).
        *reinterpret_cast<f4*>(outb + (size_t)(v0 + v) * C_ + c4) = g;
    }
}

// ---------------------------------------------------------------------------
// Kernel 2: gather. One WAVE per point (4 points / 256-thread block).
// Lane l: corner parity kk = l>>5, channel quad c4 = (l&31)*4.
// Each thread issues 4 independent float4 loads (corner pairs j=0..3)
// before any store -> 4 loads in flight, then 4 nontemporal float4 stores
// (output is write-once; NT keeps featsT resident in L2/L3).
// Per store instruction a wave writes 1 KiB contiguous.
// ---------------------------------------------------------------------------
__global__ __launch_bounds__(256) void gather_kernel(
    const float* __restrict__ ptcloud,   // (B, N, 3)
    const float* __restrict__ featsT,    // (B, V, C)
    float* __restrict__ out)             // (B, N, 8, C)
{
    const int t = threadIdx.x;
    const int point = (blockIdx.x << 2) + (t >> 6);  // 4 points per block
    const int l  = t & 63;
    const int kk = l >> 5;               // corner z-parity (0/1)
    const int c4 = (l & 31) << 2;        // channel quad base
    const int b  = point >> 15;          // N_ = 32768

    const float* pp = ptcloud + (size_t)point * 3;
    const float s = (D_ - 1) * 0.5f;     // 15.5
    const float fx = (pp[0] + 1.0f) * s;
    const float fy = (pp[1] + 1.0f) * s;
    const float fz = (pp[2] + 1.0f) * s;
    const int lx = (int)floorf(fx);
    const int ly = (int)floorf(fy);
    const int lz = (int)floorf(fz);

    const int iz = lz + kk;
    const bool vz = (unsigned)iz < (unsigned)D_;
    const int cz = min(max(iz, 0), D_ - 1);

    const float* src = featsT + (size_t)b * V_ * C_ + c4;
    float* dst = out + ((size_t)point * 8 + kk) * C_ + c4;

    f4 v[4];
    float m[4];
#pragma unroll
    for (int j = 0; j < 4; ++j) {        // corner k = 2*j + kk
        const int ix = lx + (j >> 1);
        const int iy = ly + (j & 1);
        const bool valid = vz &
                           ((unsigned)ix < (unsigned)D_) &
                           ((unsigned)iy < (unsigned)D_);
        const int cx = min(max(ix, 0), D_ - 1);
        const int cy = min(max(iy, 0), D_ - 1);
        const int flat = (cx * D_ + cy) * D_ + cz;
        v[j] = *reinterpret_cast<const f4*>(src + (size_t)flat * C_);
        m[j] = valid ? 1.0f : 0.0f;
    }

#pragma unroll
    for (int j = 0; j < 4; ++j) {
        f4 r = v[j] * m[j];
        __builtin_nontemporal_store(
            r, reinterpret_cast<f4*>(dst + (size_t)(2 * j) * C_));
    }
}

// ---------------------------------------------------------------------------
// Fallback: direct gather from (B, C, V) layout if workspace is too small
// for the transposed copy. Thread = channel; write coalesced, reads strided.
// ---------------------------------------------------------------------------
__global__ __launch_bounds__(128) void gather_direct_kernel(
    const float* __restrict__ ptcloud,   // (B, N, 3)
    const float* __restrict__ feats,     // (B, C, V)
    float* __restrict__ out)             // (B, N, 8, C)
{
    const int point = blockIdx.x;
    const int b = point >> 15;
    const int c = threadIdx.x;           // 0..127

    const float* pp = ptcloud + (size_t)point * 3;
    const float s = (D_ - 1) * 0.5f;
    const int lx = (int)floorf((pp[0] + 1.0f) * s);
    const int ly = (int)floorf((pp[1] + 1.0f) * s);
    const int lz = (int)floorf((pp[2] + 1.0f) * s);

    const float* fb = feats + ((size_t)b * C_ + c) * V_;
    float* ob = out + (size_t)point * 8 * C_ + c;

#pragma unroll
    for (int k = 0; k < 8; ++k) {
        const int ix = lx + (k >> 2);
        const int iy = ly + ((k >> 1) & 1);
        const int iz = lz + (k & 1);
        const bool valid = ((unsigned)ix < (unsigned)D_) &
                           ((unsigned)iy < (unsigned)D_) &
                           ((unsigned)iz < (unsigned)D_);
        const int cx = min(max(ix, 0), D_ - 1);
        const int cy = min(max(iy, 0), D_ - 1);
        const int cz = min(max(iz, 0), D_ - 1);
        const int flat = (cx * D_ + cy) * D_ + cz;
        ob[(size_t)k * C_] = fb[flat] * (valid ? 1.0f : 0.0f);
    }
}

extern "C" void kernel_launch(void* const* d_in, const int* in_sizes, int n_in,
                              void* d_out, int out_size, void* d_ws, size_t ws_size,
                              hipStream_t stream) {
    const float* ptcloud = (const float*)d_in[0];   // (B,N,3)
    const float* feats   = (const float*)d_in[1];   // (B,C,D,D,D)
    float* out = (float*)d_out;                     // (B,N,8,C)

    const size_t need = (size_t)B_ * C_ * V_ * sizeof(float);  // 64 MiB
    if (ws_size >= need) {
        float* featsT = (float*)d_ws;               // (B,V,C)
        dim3 tg(V_ / 32, B_);                       // (1024, 4)
        transpose_kernel<<<tg, 256, 0, stream>>>(feats, featsT);
        gather_kernel<<<(B_ * N_) / 4, 256, 0, stream>>>(ptcloud, featsT, out);
    } else {
        gather_direct_kernel<<<B_ * N_, 128, 0, stream>>>(ptcloud, feats, out);
    }
}